// Round 6
// baseline (8266.928 us; speedup 1.0000x reference)
//
#include <hip/hip_runtime.h>
#include <hip/hip_bf16.h>

using bf16x8 = __attribute__((ext_vector_type(8))) __bf16;
using short8 = __attribute__((ext_vector_type(8))) short;
using f32x4  = __attribute__((ext_vector_type(4))) float;
using f4     = __attribute__((ext_vector_type(4))) float;
using i32x4  = __attribute__((ext_vector_type(4))) int;

constexpr int NB = 128;    // batch
constexpr int NT = 256;    // time
constexpr int NH = 1024;   // hidden
constexpr int NE = 256;    // embed
constexpr int NV = 256;    // vocab

constexpr int WHH_BYTES  = 48 * 2048;   // 98304: 48 rows x 1024 bf16
constexpr int WIH0_BYTES = 48 * 512;    // 24576
constexpr int WIH1_BYTES = 48 * 1024;   // 49152 (k<512)
constexpr int GH_FLOATS  = 8 * 256;     // 8 tiles of 16x16 f32
constexpr int NBLK = 256;

// ---- cache-bypass (coherence-point) memory ops: no bulk wbl2/inv needed ----
__device__ __forceinline__ void ldg_sc(i32x4& d, const void* p) {
  asm volatile("global_load_dwordx4 %0, %1, off sc0 sc1" : "=v"(d) : "v"(p));
}
__device__ __forceinline__ void stg_sc(void* p, i32x4 v) {
  asm volatile("global_store_dwordx4 %0, %1, off sc0 sc1" :: "v"(p), "v"(v) : "memory");
}
__device__ __forceinline__ void vm0_fence() {
  asm volatile("s_waitcnt vmcnt(0)" ::: "memory");
}
__device__ __forceinline__ void use_dep(i32x4& d) {   // order consumer after fence
  asm volatile("" : "+v"(d));
}

// 8 contiguous f32 -> bf16x8 (RNE)
__device__ __forceinline__ bf16x8 cvt8(const float* p) {
  short8 r;
  #pragma unroll
  for (int j = 0; j < 8; ++j)
    r[j] = (short)__bfloat16_as_ushort(__float2bfloat16(p[j]));
  return __builtin_bit_cast(bf16x8, r);
}

__global__ __launch_bounds__(256) void embcvt_kernel(const float* __restrict__ e,
                                                     __hip_bfloat16* __restrict__ o) {
  int i = blockIdx.x * 256 + threadIdx.x;
  o[i] = __float2bfloat16(e[i]);
}

// 256 WGs x 384 threads. WG owns h'[rb*32:+32, c0:+16]. Wave wv = (mt, ks):
// mt = m-tile (16 rows), ks = K-slice; each wave computes ALL 3 gates for
// k-chunks {ks, ks+3, ...} -> each h element sc-read ONCE per WG (3x dedup).
// Gate partials combined via ds_add_f32 into zeroed sGh tiles.
// Sync: producers sc-store h' + per-WG flag; group master polls 64 flags,
// publishes ONE group-epoch line; 63 consumers poll that single line.
template<int LAYER>
__global__ __launch_bounds__(384) void gru_kernel(
    const int* __restrict__ x,
    const __hip_bfloat16* __restrict__ embb,
    const float* __restrict__ Wih,
    const float* __restrict__ Whh,
    const float* __restrict__ bih,
    const float* __restrict__ bhh,
    const float* __restrict__ h0,
    const __hip_bfloat16* __restrict__ yin,
    __hip_bfloat16* __restrict__ yout,
    __hip_bfloat16* __restrict__ hbuf,        // [2][128][1024]
    float* __restrict__ hout,
    unsigned int* __restrict__ flags)         // [4][64][16] pf + [4][16] gf
{
  extern __shared__ char smem[];
  char* sWhh = smem;
  char* sWih = smem + WHH_BYTES;
  constexpr int WIH_B = (LAYER == 0) ? WIH0_BYTES : WIH1_BYTES;
  float* sGh   = (float*)(smem + WHH_BYTES + WIH_B);
  float* sBias = sGh + GH_FLOATS;
  char*  sH    = (char*)(sBias + 64);         // 32x16 bf16 h' staging (1KB)

  const int tid  = threadIdx.x;
  const int lane = tid & 63;
  const int wv   = tid >> 6;
  const int mt   = wv & 1;
  const int ks   = wv >> 1;                   // K-slice id 0..2 (also input gate)
  const int b    = blockIdx.x;
  const int rb   = (b >> 1) & 3;
  const int cidx = (b & 1) * 32 + (b >> 3);
  const int r0   = rb * 32;
  const int c0   = cidx * 16;
  unsigned int* pf = flags + rb * 64 * 16;            // producer flags (this group)
  unsigned int* gf = flags + 4 * 64 * 16 + rb * 16;   // group epoch line
  const int slot = cidx;
  const int l16  = lane & 15;
  const int lk8  = (lane >> 4) * 8;

  // ---- stage W_hh slice swizzled (rows gate-major: gr>>4 = gate) ----
  for (int it = 0; it < 16; ++it) {
    int idx = it * 384 + tid;
    int gr = idx >> 7, kc = idx & 127;
    int grow = (gr >> 4) * NH + c0 + (gr & 15);
    short8 v = __builtin_bit_cast(short8, cvt8(Whh + grow * NH + kc * 8));
    *(short8*)(sWhh + ((gr * 2048 + kc * 16) ^ ((gr & 7) << 4))) = v;
  }
  if constexpr (LAYER == 0) {
    for (int it = 0; it < 4; ++it) {
      int idx = it * 384 + tid;
      int gr = idx >> 5, kc = idx & 31;
      int grow = (gr >> 4) * NH + c0 + (gr & 15);
      short8 v = __builtin_bit_cast(short8, cvt8(Wih + grow * NE + kc * 8));
      *(short8*)(sWih + ((gr * 512 + kc * 16) ^ ((gr & 7) << 4))) = v;
    }
  } else {
    for (int it = 0; it < 8; ++it) {
      int idx = it * 384 + tid;
      int gr = idx >> 6, kc = idx & 63;
      int grow = (gr >> 4) * NH + c0 + (gr & 15);
      short8 v = __builtin_bit_cast(short8, cvt8(Wih + grow * NH + kc * 8));
      *(short8*)(sWih + ((gr * 1024 + kc * 16) ^ ((gr & 7) << 4))) = v;
    }
  }
  if (tid < 16)       sBias[tid] = bih[c0 + tid] + bhh[c0 + tid];
  else if (tid < 32)  { int c = NH + c0 + tid - 16;   sBias[tid] = bih[c] + bhh[c]; }
  else if (tid < 48)  { int c = 2*NH + c0 + tid - 32; sBias[tid] = bih[c]; }
  else if (tid < 64)  { int c = 2*NH + c0 + tid - 48; sBias[tid] = bhh[c]; }

  // zero the accumulation tiles (ds_add targets)
  for (int i = tid; i < GH_FLOATS; i += 384) sGh[i] = 0.f;

  bf16x8 wreg[16];
  if constexpr (LAYER == 1) {
    #pragma unroll
    for (int kf = 0; kf < 16; ++kf) {
      int grow = ks * NH + c0 + l16;
      wreg[kf] = cvt8(Wih + grow * NH + 512 + kf * 32 + lk8);
    }
  }

  // ---- init h0 -> registers + sH -> sc-store to hbuf[0] + pf=1 ----
  float hown[2] = {0.f, 0.f};
  #pragma unroll
  for (int ei = 0; ei < 2; ++ei) {
    int e = tid + ei * 384;
    if (e < 512) {
      float hv = h0[(r0 + (e >> 4)) * NH + c0 + (e & 15)];
      hown[ei] = hv;
      ((unsigned short*)sH)[e] = __bfloat16_as_ushort(__float2bfloat16(hv));
    }
  }
  __syncthreads();
  if (tid < 64) {
    i32x4 hv = *(const i32x4*)(sH + (tid >> 1) * 32 + (tid & 1) * 16);
    stg_sc(hbuf + (r0 + (tid >> 1)) * NH + c0 + (tid & 1) * 8, hv);
    vm0_fence();
    if (tid == 0)
      __hip_atomic_store(pf + slot * 16, 1u, __ATOMIC_RELAXED,
                         __HIP_MEMORY_SCOPE_AGENT);
  }

  // ---- time loop ----
  for (int t = 0; t < NT; ++t) {
    const __hip_bfloat16* rbuf = hbuf + (t & 1) * (NB * NH);
    __hip_bfloat16* wbuf = hbuf + ((t + 1) & 1) * (NB * NH);
    const int arow = r0 + mt * 16 + l16;
    const int bxor = (l16 & 7) << 4;
    float* abase = sGh + (lane >> 4) * 64 + l16;

    // ---- 1. input GEMM (gate = ks, cached path, no cross-WG dep) ----
    {
      f32x4 ai = {0.f, 0.f, 0.f, 0.f};
      if constexpr (LAYER == 0) {
        int xid = x[arow * NT + t];
        const __hip_bfloat16* xptr = embb + xid * NE + lk8;
        const int bbase2 = (ks * 16 + l16) * 512 + lk8 * 2;
        #pragma unroll
        for (int kk = 0; kk < 8; ++kk) {
          bf16x8 a = __builtin_bit_cast(bf16x8, *(const short8*)(xptr + kk * 32));
          bf16x8 bb = __builtin_bit_cast(bf16x8,
              *(const short8*)(sWih + ((bbase2 + kk * 64) ^ bxor)));
          ai = __builtin_amdgcn_mfma_f32_16x16x32_bf16(a, bb, ai, 0, 0, 0);
        }
      } else {
        const __hip_bfloat16* yptr = yin + (arow * NT + t) * NH + lk8;
        const int bbase2 = (ks * 16 + l16) * 1024 + lk8 * 2;
        #pragma unroll
        for (int kk = 0; kk < 16; ++kk) {
          bf16x8 a = __builtin_bit_cast(bf16x8, *(const short8*)(yptr + kk * 32));
          bf16x8 bb = __builtin_bit_cast(bf16x8,
              *(const short8*)(sWih + ((bbase2 + kk * 64) ^ bxor)));
          ai = __builtin_amdgcn_mfma_f32_16x16x32_bf16(a, bb, ai, 0, 0, 0);
        }
        #pragma unroll
        for (int kf = 0; kf < 16; ++kf) {
          bf16x8 a = __builtin_bit_cast(bf16x8, *(const short8*)(yptr + 512 + kf * 32));
          ai = __builtin_amdgcn_mfma_f32_16x16x32_bf16(a, wreg[kf], ai, 0, 0, 0);
        }
      }
      // i_r,i_z share tiles with h_r,h_z; i_n goes to separate tiles 6/7
      float* p = abase + ((ks < 2) ? (ks * 2 + mt) : (6 + mt)) * 256;
      #pragma unroll
      for (int j = 0; j < 4; ++j) atomicAdd(p + j * 16, ai[j]);
    }

    // ---- 2. wait for all producers of h(t): master aggregates ----
    {
      unsigned int ep = (unsigned int)(t + 1);
      if (slot == 0) {                       // group master
        if (tid < 64) {
          const unsigned int* f = pf + tid * 16;
          while (__hip_atomic_load(f, __ATOMIC_RELAXED,
                                   __HIP_MEMORY_SCOPE_AGENT) < ep)
            __builtin_amdgcn_s_sleep(1);
        }
        __syncthreads();
        if (tid == 0)
          __hip_atomic_store(gf, ep, __ATOMIC_RELAXED,
                             __HIP_MEMORY_SCOPE_AGENT);
      } else {                                // consumer: poll ONE line
        if (tid == 0) {
          while (__hip_atomic_load(gf, __ATOMIC_RELAXED,
                                   __HIP_MEMORY_SCOPE_AGENT) < ep)
            __builtin_amdgcn_s_sleep(1);
        }
        __syncthreads();
      }
    }

    // ---- 3. W_hh GEMM, K-split: chunks kk = ks+3i, all 3 gates per wave ----
    {
      const int nk = (ks < 2) ? 11 : 10;
      const __hip_bfloat16* aptr = rbuf + arow * NH + lk8;
      i32x4 fr[11];
      #pragma unroll
      for (int i = 0; i < 11; ++i)
        if (i < nk) ldg_sc(fr[i], aptr + (ks + 3 * i) * 32);
      vm0_fence();
      #pragma unroll
      for (int i = 0; i < 11; ++i)
        if (i < nk) use_dep(fr[i]);

      f32x4 ah0 = {0.f,0.f,0.f,0.f}, ah1 = {0.f,0.f,0.f,0.f}, ah2 = {0.f,0.f,0.f,0.f};
      const int bb0 = (l16)      * 2048 + lk8 * 2;
      const int bb1 = (16 + l16) * 2048 + lk8 * 2;
      const int bb2 = (32 + l16) * 2048 + lk8 * 2;
      #pragma unroll
      for (int i = 0; i < 11; ++i) {
        if (i < nk) {
          int kk = ks + 3 * i;
          bf16x8 a = __builtin_bit_cast(bf16x8, fr[i]);
          bf16x8 b0 = __builtin_bit_cast(bf16x8,
              *(const short8*)(sWhh + ((bb0 + kk * 64) ^ bxor)));
          ah0 = __builtin_amdgcn_mfma_f32_16x16x32_bf16(a, b0, ah0, 0, 0, 0);
          bf16x8 b1 = __builtin_bit_cast(bf16x8,
              *(const short8*)(sWhh + ((bb1 + kk * 64) ^ bxor)));
          ah1 = __builtin_amdgcn_mfma_f32_16x16x32_bf16(a, b1, ah1, 0, 0, 0);
          bf16x8 b2 = __builtin_bit_cast(bf16x8,
              *(const short8*)(sWhh + ((bb2 + kk * 64) ^ bxor)));
          ah2 = __builtin_amdgcn_mfma_f32_16x16x32_bf16(a, b2, ah2, 0, 0, 0);
        }
      }
      float* p0 = abase + (0 + mt) * 256;
      float* p1 = abase + (2 + mt) * 256;
      float* p2 = abase + (4 + mt) * 256;
      #pragma unroll
      for (int j = 0; j < 4; ++j) {
        atomicAdd(p0 + j * 16, ah0[j]);
        atomicAdd(p1 + j * 16, ah1[j]);
        atomicAdd(p2 + j * 16, ah2[j]);
      }
    }
    __syncthreads();

    // ---- 4. gates (f32); read sGh slots then zero them for next step ----
    #pragma unroll
    for (int ei = 0; ei < 2; ++ei) {
      int e = tid + ei * 384;
      if (e < 512) {
        int lrow = e >> 4, lcol = e & 15;
        int m2 = lrow >> 4, tr = lrow & 15;
        float* s0 = sGh + (0 + m2) * 256 + tr * 16 + lcol;
        float* s1 = sGh + (2 + m2) * 256 + tr * 16 + lcol;
        float* s2 = sGh + (4 + m2) * 256 + tr * 16 + lcol;
        float* s3 = sGh + (6 + m2) * 256 + tr * 16 + lcol;
        float ghr = *s0, ghz = *s1, ghn = *s2, gin = *s3;
        *s0 = 0.f; *s1 = 0.f; *s2 = 0.f; *s3 = 0.f;
        float r = 1.f / (1.f + __expf(-(ghr + sBias[lcol])));
        float z = 1.f / (1.f + __expf(-(ghz + sBias[16 + lcol])));
        float npre = (gin + sBias[32 + lcol]) + r * (ghn + sBias[48 + lcol]);
        float n = 2.f / (1.f + __expf(-2.f * npre)) - 1.f;   // tanh, inf-safe
        float hn = (1.f - z) * n + z * hown[ei];
        hown[ei] = hn;
        __hip_bfloat16 hb = __float2bfloat16(hn);
        ((unsigned short*)sH)[e] = __bfloat16_as_ushort(hb);
        if constexpr (LAYER == 0)
          yout[((r0 + lrow) * NT + t) * NH + c0 + lcol] = hb;
      }
    }

    // ---- 5. publish h' (sc-store) + pf epoch t+2 ----
    __syncthreads();
    if (tid < 64) {
      i32x4 hv = *(const i32x4*)(sH + (tid >> 1) * 32 + (tid & 1) * 16);
      stg_sc(wbuf + (r0 + (tid >> 1)) * NH + c0 + (tid & 1) * 8, hv);
      vm0_fence();
      if (tid == 0)
        __hip_atomic_store(pf + slot * 16, (unsigned int)(t + 2),
                           __ATOMIC_RELAXED, __HIP_MEMORY_SCOPE_AGENT);
    }
  }

  #pragma unroll
  for (int ei = 0; ei < 2; ++ei) {
    int e = tid + ei * 384;
    if (e < 512) {
      int lrow = e >> 4, lcol = e & 15;
      hout[(r0 + lrow) * NH + c0 + lcol] = hown[ei];
    }
  }
}

__global__ __launch_bounds__(256) void logits_kernel(
    const __hip_bfloat16* __restrict__ h1,
    const float* __restrict__ fcW,
    const float* __restrict__ fcb,
    float* __restrict__ out)
{
  __shared__ float hrow[NH];
  int b = blockIdx.x, v = threadIdx.x;
  for (int i = v; i < NH; i += 256) hrow[i] = __bfloat162float(h1[b * NH + i]);
  __syncthreads();
  float acc = fcb[v];
  for (int k = 0; k < NH; k += 4) {
    f4 wv = *(const f4*)(fcW + v * NH + k);
    #pragma unroll
    for (int j = 0; j < 4; ++j) acc += wv[j] * hrow[k + j];
  }
  out[b * NV + v] = acc;
}

extern "C" void kernel_launch(void* const* d_in, const int* in_sizes, int n_in,
                              void* d_out, int out_size, void* d_ws, size_t ws_size,
                              hipStream_t stream) {
  const int*   x    = (const int*)d_in[0];
  const float* h0   = (const float*)d_in[1];
  const float* emb  = (const float*)d_in[2];
  const float* Wih0 = (const float*)d_in[3];
  const float* Whh0 = (const float*)d_in[4];
  const float* bih0 = (const float*)d_in[5];
  const float* bhh0 = (const float*)d_in[6];
  const float* Wih1 = (const float*)d_in[7];
  const float* Whh1 = (const float*)d_in[8];
  const float* bih1 = (const float*)d_in[9];
  const float* bhh1 = (const float*)d_in[10];
  const float* fcW  = (const float*)d_in[11];
  const float* fcb  = (const float*)d_in[12];
  float* out = (float*)d_out;

  char* ws = (char*)d_ws;
  size_t off = 0;
  __hip_bfloat16* y0   = (__hip_bfloat16*)ws;            off += (size_t)NB * NT * NH * 2;
  __hip_bfloat16* hbuf = (__hip_bfloat16*)(ws + off);    off += (size_t)2 * NB * NH * 2;
  __hip_bfloat16* embb = (__hip_bfloat16*)(ws + off);    off += (size_t)NV * NE * 2;
  unsigned int*  flags0 = (unsigned int*)(ws + off);     off += 17408;  // pf 16KB + gf
  unsigned int*  flags1 = (unsigned int*)(ws + off);     off += 17408;

  (void)hipMemsetAsync(flags0, 0, 2 * 17408, stream);
  embcvt_kernel<<<dim3(NV * NE / 256), dim3(256), 0, stream>>>(emb, embb);

  constexpr int lds0 = WHH_BYTES + WIH0_BYTES + GH_FLOATS * 4 + 64 * 4 + 1024;  // 132352
  constexpr int lds1 = WHH_BYTES + WIH1_BYTES + GH_FLOATS * 4 + 64 * 4 + 1024;  // 156928
  (void)hipFuncSetAttribute(reinterpret_cast<const void*>(gru_kernel<0>),
                            hipFuncAttributeMaxDynamicSharedMemorySize, lds0);
  (void)hipFuncSetAttribute(reinterpret_cast<const void*>(gru_kernel<1>),
                            hipFuncAttributeMaxDynamicSharedMemorySize, lds1);

  gru_kernel<0><<<dim3(NBLK), dim3(384), lds0, stream>>>(
      x, embb, Wih0, Whh0, bih0, bhh0, h0, y0, y0, hbuf, out + 32768, flags0);
  gru_kernel<1><<<dim3(NBLK), dim3(384), lds1, stream>>>(
      x, embb, Wih1, Whh1, bih1, bhh1, h0 + NB * NH, y0, y0, hbuf,
      out + 32768 + NB * NH, flags1);
  logits_kernel<<<dim3(NB), dim3(256), 0, stream>>>(hbuf, fcW, fcb, out);
}

// Round 7
// 4081.963 us; speedup vs baseline: 2.0252x; 2.0252x over previous
//
#include <hip/hip_runtime.h>
#include <hip/hip_bf16.h>

using bf16x8 = __attribute__((ext_vector_type(8))) __bf16;
using short8 = __attribute__((ext_vector_type(8))) short;
using f32x4  = __attribute__((ext_vector_type(4))) float;
using f4     = __attribute__((ext_vector_type(4))) float;
using i32x4  = __attribute__((ext_vector_type(4))) int;

constexpr int NB = 128;    // batch
constexpr int NT = 256;    // time
constexpr int NH = 1024;   // hidden
constexpr int NE = 256;    // embed
constexpr int NV = 256;    // vocab

constexpr int WHH_BYTES = 48 * 2048;    // 98304: 48 rows x 1024 bf16
constexpr int GH_FLOATS = 24 * 256;     // 18 hh-partial tiles + 6 input tiles
constexpr int NBLK = 256;

// ---- cache-bypass (coherence-point) memory ops: no bulk wbl2/inv needed ----
__device__ __forceinline__ void ldg_sc(i32x4& d, const void* p) {
  asm volatile("global_load_dwordx4 %0, %1, off sc0 sc1" : "=v"(d) : "v"(p));
}
__device__ __forceinline__ void stg_sc(void* p, i32x4 v) {
  asm volatile("global_store_dwordx4 %0, %1, off sc0 sc1" :: "v"(p), "v"(v) : "memory");
}
__device__ __forceinline__ void vm0_fence() {
  asm volatile("s_waitcnt vmcnt(0)" ::: "memory");
}
__device__ __forceinline__ void use_dep(i32x4& d) {
  asm volatile("" : "+v"(d));
}

// 8 contiguous f32 -> bf16x8 (RNE)
__device__ __forceinline__ bf16x8 cvt8(const float* p) {
  short8 r;
  #pragma unroll
  for (int j = 0; j < 8; ++j)
    r[j] = (short)__bfloat16_as_ushort(__float2bfloat16(p[j]));
  return __builtin_bit_cast(bf16x8, r);
}

__global__ __launch_bounds__(256) void embcvt_kernel(const float* __restrict__ e,
                                                     __hip_bfloat16* __restrict__ o) {
  int i = blockIdx.x * 256 + threadIdx.x;
  o[i] = __float2bfloat16(e[i]);
}

// 256 WGs x 384 threads. WG owns h'[rb*32:+32, c0:+16]. Wave wv=(mt,ks):
// mt = 16-row m-tile, ks = K-slice 0..2 (doubles as input-GEMM gate).
// Each wave sc-reads its A k-slice ONCE and computes all 3 gates from regs;
// partials land in DISJOINT sGh regions [ks][mt][gate] (no atomics).
// W_ih lives entirely in VGPR fragments. Sync = R5's direct 64-flag poll.
template<int LAYER>
__global__ __launch_bounds__(384) void gru_kernel(
    const int* __restrict__ x,
    const __hip_bfloat16* __restrict__ embb,
    const float* __restrict__ Wih,
    const float* __restrict__ Whh,
    const float* __restrict__ bih,
    const float* __restrict__ bhh,
    const float* __restrict__ h0,
    const __hip_bfloat16* __restrict__ yin,
    __hip_bfloat16* __restrict__ yout,
    __hip_bfloat16* __restrict__ hbuf,        // [2][128][1024]
    float* __restrict__ hout,
    unsigned int* __restrict__ flags)         // [4][64][16] uints
{
  extern __shared__ char smem[];
  char*  sWhh  = smem;
  float* sGh   = (float*)(smem + WHH_BYTES);
  float* sBias = sGh + GH_FLOATS;
  char*  sH    = (char*)(sBias + 64);         // 32x16 bf16 h' staging (1KB)

  const int tid  = threadIdx.x;
  const int lane = tid & 63;
  const int wv   = tid >> 6;
  const int mt   = wv & 1;
  const int ks   = wv >> 1;                   // K-slice / input gate, 0..2
  const int b    = blockIdx.x;
  const int rb   = (b >> 1) & 3;
  const int cidx = (b & 1) * 32 + (b >> 3);
  const int r0   = rb * 32;
  const int c0   = cidx * 16;
  unsigned int* pf = flags + rb * 64 * 16;
  const int slot = cidx;
  const int l16  = lane & 15;
  const int lk8  = (lane >> 4) * 8;

  // ---- stage W_hh slice swizzled (rows gate-major: gr>>4 = gate) ----
  for (int it = 0; it < 16; ++it) {
    int idx = it * 384 + tid;
    int gr = idx >> 7, kc = idx & 127;
    int grow = (gr >> 4) * NH + c0 + (gr & 15);
    short8 v = __builtin_bit_cast(short8, cvt8(Whh + grow * NH + kc * 8));
    *(short8*)(sWhh + ((gr * 2048 + kc * 16) ^ ((gr & 7) << 4))) = v;
  }
  if (tid < 16)       sBias[tid] = bih[c0 + tid] + bhh[c0 + tid];
  else if (tid < 32)  { int c = NH + c0 + tid - 16;   sBias[tid] = bih[c] + bhh[c]; }
  else if (tid < 48)  { int c = 2*NH + c0 + tid - 32; sBias[tid] = bih[c]; }
  else if (tid < 64)  { int c = 2*NH + c0 + tid - 48; sBias[tid] = bhh[c]; }

  // ---- W_ih fully in VGPR fragments (wave's input gate = ks) ----
  constexpr int NFRAG = (LAYER == 0) ? 8 : 32;
  constexpr int KIN   = (LAYER == 0) ? NE : NH;
  bf16x8 wreg[NFRAG];
  #pragma unroll
  for (int kf = 0; kf < NFRAG; ++kf) {
    int grow = ks * NH + c0 + l16;
    wreg[kf] = cvt8(Wih + grow * KIN + kf * 32 + lk8);
  }

  // ---- init h0 -> regs + sH -> sc-store hbuf[0] + flag=1 ----
  float hown[2] = {0.f, 0.f};
  #pragma unroll
  for (int ei = 0; ei < 2; ++ei) {
    int e = tid + ei * 384;
    if (e < 512) {
      float hv = h0[(r0 + (e >> 4)) * NH + c0 + (e & 15)];
      hown[ei] = hv;
      ((unsigned short*)sH)[e] = __bfloat16_as_ushort(__float2bfloat16(hv));
    }
  }
  __syncthreads();
  if (tid < 64) {
    i32x4 hv = *(const i32x4*)(sH + (tid >> 1) * 32 + (tid & 1) * 16);
    stg_sc(hbuf + (r0 + (tid >> 1)) * NH + c0 + (tid & 1) * 8, hv);
    vm0_fence();
    if (tid == 0)
      __hip_atomic_store(pf + slot * 16, 1u, __ATOMIC_RELAXED,
                         __HIP_MEMORY_SCOPE_AGENT);
  }

  // ---- time loop ----
  for (int t = 0; t < NT; ++t) {
    const __hip_bfloat16* rbuf = hbuf + (t & 1) * (NB * NH);
    __hip_bfloat16* wbuf = hbuf + ((t + 1) & 1) * (NB * NH);
    const int arow = r0 + mt * 16 + l16;
    const int bxor = (l16 & 7) << 4;
    float* abase = sGh + (lane >> 4) * 64 + l16;

    // ---- 1a. input GEMM part 1 (cached, overlaps producers' publish) ----
    constexpr int P1 = (LAYER == 0) ? 4 : 24;
    f32x4 ai = {0.f, 0.f, 0.f, 0.f};
    const __hip_bfloat16* xptr;
    if constexpr (LAYER == 0) {
      int xid = x[arow * NT + t];
      xptr = embb + xid * NE + lk8;
    } else {
      xptr = yin + (arow * NT + t) * NH + lk8;
    }
    #pragma unroll
    for (int kk = 0; kk < P1; ++kk) {
      bf16x8 a = __builtin_bit_cast(bf16x8, *(const short8*)(xptr + kk * 32));
      ai = __builtin_amdgcn_mfma_f32_16x16x32_bf16(a, wreg[kk], ai, 0, 0, 0);
    }

    // ---- 2. wait for all producers of h(t) (direct 64-flag poll) ----
    {
      unsigned int ep = (unsigned int)(t + 1);
      if (tid < 64) {
        const unsigned int* f = pf + tid * 16;
        while (__hip_atomic_load(f, __ATOMIC_RELAXED,
                                 __HIP_MEMORY_SCOPE_AGENT) < ep)
          __builtin_amdgcn_s_sleep(1);
      }
      __syncthreads();
    }

    // ---- 3a. issue ALL A sc-loads for this wave's k-slice ----
    const int nk = (ks < 2) ? 11 : 10;
    const __hip_bfloat16* aptr = rbuf + arow * NH + lk8;
    i32x4 fr[11];
    #pragma unroll
    for (int i = 0; i < 11; ++i)
      if (i < nk) ldg_sc(fr[i], aptr + (ks + 3 * i) * 32);

    // ---- 1b. input GEMM part 2 (hides A-load round trip) ----
    #pragma unroll
    for (int kk = P1; kk < NFRAG; ++kk) {
      bf16x8 a = __builtin_bit_cast(bf16x8, *(const short8*)(xptr + kk * 32));
      ai = __builtin_amdgcn_mfma_f32_16x16x32_bf16(a, wreg[kk], ai, 0, 0, 0);
    }
    {   // input partial -> sGh tile [18 + mt*3 + ks]
      float* p = abase + (18 + mt * 3 + ks) * 256;
      p[0] = ai[0]; p[16] = ai[1]; p[32] = ai[2]; p[48] = ai[3];
    }

    // ---- 3b. W_hh MFMAs: A from regs, all 3 gates per chunk ----
    vm0_fence();
    #pragma unroll
    for (int i = 0; i < 11; ++i)
      if (i < nk) use_dep(fr[i]);
    {
      f32x4 ah0 = {0.f,0.f,0.f,0.f}, ah1 = {0.f,0.f,0.f,0.f}, ah2 = {0.f,0.f,0.f,0.f};
      const int bb0 = (l16)      * 2048 + lk8 * 2;
      const int bb1 = (16 + l16) * 2048 + lk8 * 2;
      const int bb2 = (32 + l16) * 2048 + lk8 * 2;
      #pragma unroll
      for (int i = 0; i < 11; ++i) {
        if (i < nk) {
          int kk = ks + 3 * i;
          bf16x8 a = __builtin_bit_cast(bf16x8, fr[i]);
          bf16x8 b0 = __builtin_bit_cast(bf16x8,
              *(const short8*)(sWhh + ((bb0 + kk * 64) ^ bxor)));
          ah0 = __builtin_amdgcn_mfma_f32_16x16x32_bf16(a, b0, ah0, 0, 0, 0);
          bf16x8 b1 = __builtin_bit_cast(bf16x8,
              *(const short8*)(sWhh + ((bb1 + kk * 64) ^ bxor)));
          ah1 = __builtin_amdgcn_mfma_f32_16x16x32_bf16(a, b1, ah1, 0, 0, 0);
          bf16x8 b2 = __builtin_bit_cast(bf16x8,
              *(const short8*)(sWhh + ((bb2 + kk * 64) ^ bxor)));
          ah2 = __builtin_amdgcn_mfma_f32_16x16x32_bf16(a, b2, ah2, 0, 0, 0);
        }
      }
      // partials -> disjoint tiles [ks*6 + mt*3 + g]
      float* p0 = abase + (ks * 6 + mt * 3 + 0) * 256;
      float* p1 = abase + (ks * 6 + mt * 3 + 1) * 256;
      float* p2 = abase + (ks * 6 + mt * 3 + 2) * 256;
      p0[0] = ah0[0]; p0[16] = ah0[1]; p0[32] = ah0[2]; p0[48] = ah0[3];
      p1[0] = ah1[0]; p1[16] = ah1[1]; p1[32] = ah1[2]; p1[48] = ah1[3];
      p2[0] = ah2[0]; p2[16] = ah2[1]; p2[32] = ah2[2]; p2[48] = ah2[3];
    }
    __syncthreads();

    // ---- 4. gates: sum 3 ks-partials + input, f32 h in registers ----
    #pragma unroll
    for (int ei = 0; ei < 2; ++ei) {
      int e = tid + ei * 384;
      if (e < 512) {
        int lrow = e >> 4, lcol = e & 15;
        int m2 = lrow >> 4, off = (lrow & 15) * 16 + lcol;
        float ghr = sGh[(0*6 + m2*3 + 0) * 256 + off]
                  + sGh[(1*6 + m2*3 + 0) * 256 + off]
                  + sGh[(2*6 + m2*3 + 0) * 256 + off];
        float ghz = sGh[(0*6 + m2*3 + 1) * 256 + off]
                  + sGh[(1*6 + m2*3 + 1) * 256 + off]
                  + sGh[(2*6 + m2*3 + 1) * 256 + off];
        float ghn = sGh[(0*6 + m2*3 + 2) * 256 + off]
                  + sGh[(1*6 + m2*3 + 2) * 256 + off]
                  + sGh[(2*6 + m2*3 + 2) * 256 + off];
        float gir = sGh[(18 + m2*3 + 0) * 256 + off];
        float giz = sGh[(18 + m2*3 + 1) * 256 + off];
        float gin = sGh[(18 + m2*3 + 2) * 256 + off];
        float r = 1.f / (1.f + __expf(-(gir + ghr + sBias[lcol])));
        float z = 1.f / (1.f + __expf(-(giz + ghz + sBias[16 + lcol])));
        float npre = (gin + sBias[32 + lcol]) + r * (ghn + sBias[48 + lcol]);
        float n = 2.f / (1.f + __expf(-2.f * npre)) - 1.f;   // tanh, inf-safe
        float hn = (1.f - z) * n + z * hown[ei];
        hown[ei] = hn;
        __hip_bfloat16 hb = __float2bfloat16(hn);
        ((unsigned short*)sH)[e] = __bfloat16_as_ushort(hb);
        if constexpr (LAYER == 0)
          yout[((r0 + lrow) * NT + t) * NH + c0 + lcol] = hb;
      }
    }

    // ---- 5. publish h' (sc-store) + flag epoch t+2 ----
    __syncthreads();
    if (tid < 64) {
      i32x4 hv = *(const i32x4*)(sH + (tid >> 1) * 32 + (tid & 1) * 16);
      stg_sc(wbuf + (r0 + (tid >> 1)) * NH + c0 + (tid & 1) * 8, hv);
      vm0_fence();
      if (tid == 0)
        __hip_atomic_store(pf + slot * 16, (unsigned int)(t + 2),
                           __ATOMIC_RELAXED, __HIP_MEMORY_SCOPE_AGENT);
    }
  }

  #pragma unroll
  for (int ei = 0; ei < 2; ++ei) {
    int e = tid + ei * 384;
    if (e < 512) {
      int lrow = e >> 4, lcol = e & 15;
      hout[(r0 + lrow) * NH + c0 + lcol] = hown[ei];
    }
  }
}

__global__ __launch_bounds__(256) void logits_kernel(
    const __hip_bfloat16* __restrict__ h1,
    const float* __restrict__ fcW,
    const float* __restrict__ fcb,
    float* __restrict__ out)
{
  __shared__ float hrow[NH];
  int b = blockIdx.x, v = threadIdx.x;
  // sc-read h1 (written by gru with sc-stores; avoid stale L2 across replays)
  if (v < 128) {
    i32x4 hv;
    ldg_sc(hv, h1 + b * NH + v * 8);
    vm0_fence();
    use_dep(hv);
    short8 s = __builtin_bit_cast(short8, hv);
    #pragma unroll
    for (int j = 0; j < 8; ++j) {
      union { unsigned int i; float f; } c;
      c.i = ((unsigned int)(unsigned short)s[j]) << 16;
      hrow[v * 8 + j] = c.f;
    }
  }
  __syncthreads();
  float acc = fcb[v];
  for (int k = 0; k < NH; k += 4) {
    f4 wv = *(const f4*)(fcW + v * NH + k);
    #pragma unroll
    for (int j = 0; j < 4; ++j) acc += wv[j] * hrow[k + j];
  }
  out[b * NV + v] = acc;
}

extern "C" void kernel_launch(void* const* d_in, const int* in_sizes, int n_in,
                              void* d_out, int out_size, void* d_ws, size_t ws_size,
                              hipStream_t stream) {
  const int*   x    = (const int*)d_in[0];
  const float* h0   = (const float*)d_in[1];
  const float* emb  = (const float*)d_in[2];
  const float* Wih0 = (const float*)d_in[3];
  const float* Whh0 = (const float*)d_in[4];
  const float* bih0 = (const float*)d_in[5];
  const float* bhh0 = (const float*)d_in[6];
  const float* Wih1 = (const float*)d_in[7];
  const float* Whh1 = (const float*)d_in[8];
  const float* bih1 = (const float*)d_in[9];
  const float* bhh1 = (const float*)d_in[10];
  const float* fcW  = (const float*)d_in[11];
  const float* fcb  = (const float*)d_in[12];
  float* out = (float*)d_out;

  char* ws = (char*)d_ws;
  size_t off = 0;
  __hip_bfloat16* y0   = (__hip_bfloat16*)ws;            off += (size_t)NB * NT * NH * 2;
  __hip_bfloat16* hbuf = (__hip_bfloat16*)(ws + off);    off += (size_t)2 * NB * NH * 2;
  __hip_bfloat16* embb = (__hip_bfloat16*)(ws + off);    off += (size_t)NV * NE * 2;
  unsigned int*  flags0 = (unsigned int*)(ws + off);     off += 4 * 64 * 16 * 4;
  unsigned int*  flags1 = (unsigned int*)(ws + off);     off += 4 * 64 * 16 * 4;

  (void)hipMemsetAsync(flags0, 0, 2 * 4 * 64 * 16 * 4, stream);
  embcvt_kernel<<<dim3(NV * NE / 256), dim3(256), 0, stream>>>(emb, embb);

  constexpr int lds = WHH_BYTES + GH_FLOATS * 4 + 64 * 4 + 1024;  // 124160
  (void)hipFuncSetAttribute(reinterpret_cast<const void*>(gru_kernel<0>),
                            hipFuncAttributeMaxDynamicSharedMemorySize, lds);
  (void)hipFuncSetAttribute(reinterpret_cast<const void*>(gru_kernel<1>),
                            hipFuncAttributeMaxDynamicSharedMemorySize, lds);

  gru_kernel<0><<<dim3(NBLK), dim3(384), lds, stream>>>(
      x, embb, Wih0, Whh0, bih0, bhh0, h0, y0, y0, hbuf, out + 32768, flags0);
  gru_kernel<1><<<dim3(NBLK), dim3(384), lds, stream>>>(
      x, embb, Wih1, Whh1, bih1, bhh1, h0 + NB * NH, y0, y0, hbuf,
      out + 32768 + NB * NH, flags1);
  logits_kernel<<<dim3(NB), dim3(256), 0, stream>>>(hbuf, fcW, fcb, out);
}